// Round 1
// baseline (125.395 us; speedup 1.0000x reference)
//
#include <hip/hip_runtime.h>

// Problem constants (match reference)
constexpr int U_ = 256;
constexpr int I_ = 512;
constexpr int J_ = 31;          // neighbors
constexpr int UI = U_ * I_;     // 131072 (u,i) pairs
// E_IN=3, N_EMB=10, N_FIT=32, K=2

struct NbrData { float s0, s1, s2; float4 r; };

__device__ __forceinline__ NbrData load_nbr(const float* __restrict__ sg,
                                            const float* __restrict__ rr, int j) {
    NbrData d;
    d.s0 = sg[j * 3 + 0];
    d.s1 = sg[j * 3 + 1];
    d.s2 = sg[j * 3 + 2];
    d.r  = *reinterpret_cast<const float4*>(rr + j * 4);  // 16B-aligned: pair*496 + j*16
    return d;
}

__global__ __launch_bounds__(256, 2) void dqn_fused(
    const float* __restrict__ Sg,  const float* __restrict__ R,
    const float* __restrict__ W1,  const float* __restrict__ b1,
    const float* __restrict__ W2,  const float* __restrict__ b2,
    const float* __restrict__ Wf1, const float* __restrict__ bf1,
    const float* __restrict__ Wf2, const float* __restrict__ bf2,
    const float* __restrict__ Wf3, const float* __restrict__ bf3,
    float* __restrict__ out)
{
    const int pair = blockIdx.x * 256 + threadIdx.x;
    const float* sg = Sg + (size_t)pair * (J_ * 3);
    const float* rr = R  + (size_t)pair * (J_ * 4);

    // Hoist embedding layer-1 weights into registers (uniform loads, L1/K$-hot)
    float w1[3][10], c1[10];
    #pragma unroll
    for (int k = 0; k < 3; ++k)
        #pragma unroll
        for (int p = 0; p < 10; ++p) w1[k][p] = W1[k * 10 + p];
    #pragma unroll
    for (int p = 0; p < 10; ++p) c1[p] = b1[p];

    // Accumulators: M[l][p] = sum_j R_j[l] * h_j[p]  ;  Rs[l] = sum_j R_j[l]
    float M[4][10];
    float Rs[4] = {0.f, 0.f, 0.f, 0.f};
    #pragma unroll
    for (int l = 0; l < 4; ++l)
        #pragma unroll
        for (int p = 0; p < 10; ++p) M[l][p] = 0.f;

    auto process = [&](const NbrData& nb) {
        float h[10];
        #pragma unroll
        for (int p = 0; p < 10; ++p) {
            float t = c1[p] + nb.s0 * w1[0][p] + nb.s1 * w1[1][p] + nb.s2 * w1[2][p];
            h[p] = t > 0.f ? t : 0.f;   // ReLU
        }
        Rs[0] += nb.r.x; Rs[1] += nb.r.y; Rs[2] += nb.r.z; Rs[3] += nb.r.w;
        #pragma unroll
        for (int p = 0; p < 10; ++p) {
            M[0][p] += nb.r.x * h[p];
            M[1][p] += nb.r.y * h[p];
            M[2][p] += nb.r.z * h[p];
            M[3][p] += nb.r.w * h[p];
        }
    };

    // Depth-2 software pipeline over neighbors (J_ = 31, odd)
    NbrData A = load_nbr(sg, rr, 0);
    NbrData B = load_nbr(sg, rr, 1);
    #pragma unroll 1
    for (int jj = 0; jj + 1 < J_; jj += 2) {      // jj = 0,2,...,28 : process jj, jj+1
        NbrData C = load_nbr(sg, rr, jj + 2);     // jj+2 <= 30, always valid
        NbrData D2 = C;
        if (jj + 3 < J_) D2 = load_nbr(sg, rr, jj + 3);
        process(A);
        process(B);
        A = C;
        B = D2;
    }
    process(A);   // j = 30

    // T2[l][n] = sum_p M[l][p] * W2[p][n] + Rs[l] * b2[n]   (T1[k][l] == T2[l][k])
    float T2[4][10];
    #pragma unroll
    for (int l = 0; l < 4; ++l) {
        #pragma unroll
        for (int n = 0; n < 10; ++n) T2[l][n] = Rs[l] * b2[n];
    }
    #pragma unroll
    for (int p = 0; p < 10; ++p) {
        float w2row[10];
        #pragma unroll
        for (int n = 0; n < 10; ++n) w2row[n] = W2[p * 10 + n];
        #pragma unroll
        for (int l = 0; l < 4; ++l) {
            float m = M[l][p];
            #pragma unroll
            for (int n = 0; n < 10; ++n) T2[l][n] += m * w2row[n];
        }
    }

    // D[k*10+n] = sum_l T2[l][k] * T2[l][n]   (k < 2)
    float D[20];
    #pragma unroll
    for (int k = 0; k < 2; ++k)
        #pragma unroll
        for (int n = 0; n < 10; ++n) {
            D[k * 10 + n] = T2[0][k] * T2[0][n] + T2[1][k] * T2[1][n]
                          + T2[2][k] * T2[2][n] + T2[3][k] * T2[3][n];
        }

    // Fit MLP: 20 -> 32 -> 32 -> 1 (weights read as uniform float4 rows)
    float f1[32];
    #pragma unroll
    for (int o = 0; o < 32; ++o) f1[o] = bf1[o];
    #pragma unroll
    for (int kk = 0; kk < 20; ++kk) {
        const float4* wrow = reinterpret_cast<const float4*>(Wf1 + kk * 32);
        float d = D[kk];
        #pragma unroll
        for (int v = 0; v < 8; ++v) {
            float4 w = wrow[v];
            f1[4 * v + 0] += d * w.x;
            f1[4 * v + 1] += d * w.y;
            f1[4 * v + 2] += d * w.z;
            f1[4 * v + 3] += d * w.w;
        }
    }
    #pragma unroll
    for (int o = 0; o < 32; ++o) f1[o] = f1[o] > 0.f ? f1[o] : 0.f;

    float f2[32];
    #pragma unroll
    for (int o = 0; o < 32; ++o) f2[o] = bf2[o];
    #pragma unroll
    for (int kk = 0; kk < 32; ++kk) {
        const float4* wrow = reinterpret_cast<const float4*>(Wf2 + kk * 32);
        float d = f1[kk];
        #pragma unroll
        for (int v = 0; v < 8; ++v) {
            float4 w = wrow[v];
            f2[4 * v + 0] += d * w.x;
            f2[4 * v + 1] += d * w.y;
            f2[4 * v + 2] += d * w.z;
            f2[4 * v + 3] += d * w.w;
        }
    }
    #pragma unroll
    for (int o = 0; o < 32; ++o) f2[o] = f2[o] > 0.f ? f2[o] : 0.f;

    float q = bf3[0];
    #pragma unroll
    for (int o = 0; o < 32; o += 4) {
        float4 w = *reinterpret_cast<const float4*>(Wf3 + o);
        q += f2[o + 0] * w.x + f2[o + 1] * w.y + f2[o + 2] * w.z + f2[o + 3] * w.w;
    }

    out[pair] = q;
}

extern "C" void kernel_launch(void* const* d_in, const int* in_sizes, int n_in,
                              void* d_out, int out_size, void* d_ws, size_t ws_size,
                              hipStream_t stream) {
    const float* Sg  = (const float*)d_in[0];
    const float* R   = (const float*)d_in[1];
    const float* W1  = (const float*)d_in[2];
    const float* b1  = (const float*)d_in[3];
    const float* W2  = (const float*)d_in[4];
    const float* b2  = (const float*)d_in[5];
    const float* Wf1 = (const float*)d_in[6];
    const float* bf1 = (const float*)d_in[7];
    const float* Wf2 = (const float*)d_in[8];
    const float* bf2 = (const float*)d_in[9];
    const float* Wf3 = (const float*)d_in[10];
    const float* bf3 = (const float*)d_in[11];
    float* out = (float*)d_out;

    dim3 grid(UI / 256), block(256);
    dqn_fused<<<grid, block, 0, stream>>>(Sg, R, W1, b1, W2, b2,
                                          Wf1, bf1, Wf2, bf2, Wf3, bf3, out);
}